// Round 1
// baseline (2530.940 us; speedup 1.0000x reference)
//
#include <hip/hip_runtime.h>
#include <stdint.h>

// Problem constants
#define B_    64
#define L_    512
#define EMB_  128
#define HID_  256
#define OUT_  32

typedef float    f32x4  __attribute__((ext_vector_type(4)));
typedef _Float16 f16x4v __attribute__((ext_vector_type(4)));
typedef _Float16 f16x8v __attribute__((ext_vector_type(8)));

#define MFMA(a,b,c) __builtin_amdgcn_mfma_f32_16x16x32_f16((a),(b),(c),0,0,0)

__device__ __forceinline__ float sigf(float x){ return 1.f/(1.f+__expf(-x)); }
__device__ __forceinline__ float tanhf_(float x){ float e=__expf(2.f*x); return 1.f-2.f/(e+1.f); }

__device__ __forceinline__ f16x4v cvt4(const float4 v){
  f16x4v r = {(_Float16)v.x,(_Float16)v.y,(_Float16)v.z,(_Float16)v.w};
  return r;
}

// MFMA 16x16x32 fragment convention used throughout (lane = 16*g + r):
//   A[16m x 32k]: row = r, k = kt*32 + (j<4 ? 4g+j : 16+4g+(j-4))
//   B[32k x 16n]: col = r, same k mapping
//   D f32x4:      row(m) = 4g+reg, col(n) = r            [m89 HW-verified]

// ---------------- Phase 1: Wx[dir][l][row(1024)][b(64)] f16 = x@Wih^T + bih + bhh
// grid 512*16, block 256; each block: one l, 128 gate rows.
__global__ __launch_bounds__(256) void k_wx(
    const int* __restrict__ sents, const float* __restrict__ emb,
    const float* __restrict__ WihF, const float* __restrict__ WihB,
    const float* __restrict__ bihF, const float* __restrict__ bhhF,
    const float* __restrict__ bihB, const float* __restrict__ bhhB,
    _Float16* __restrict__ wx)
{
  __shared__ _Float16 Af[4*4*64*8];   // 16 KB  x-tile fragments [mt][kt][lane][8]
  __shared__ _Float16 Bf[8*4*64*8];   // 32 KB  Wih fragments [nt][kt][lane][8]
  __shared__ _Float16 Tt[128*64];     // 16 KB  [col][b] out tile
  const int bid = blockIdx.x;
  const int l   = bid >> 4;
  const int ntb = bid & 15;
  const int dir = ntb >> 3;
  const int tid = threadIdx.x;

  // stage x tile (gather embedding rows, fp32 -> f16) into fragment order
  for (int it = 0; it < 8; ++it) {
    int cid = it*256 + tid;               // 2048 = 64 b * 32 quad-chunks
    int b = cid >> 5, ec = cid & 31, e0 = ec*4;
    int tok = sents[b*L_ + l];
    float4 v = *(const float4*)(emb + (size_t)tok*EMB_ + e0);
    int g = ec & 3, hi = (ec>>2)&1, kt = ec>>3;
    int lane = g*16 + (b&15), mt = b>>4;
    *(f16x4v*)&Af[(((mt*4+kt)*64 + lane)<<3) + hi*4] = cvt4(v);
  }
  const float* Wih = dir ? WihB : WihF;
  for (int it = 0; it < 16; ++it) {
    int cid = it*256 + tid;               // 4096 = 128 cols * 32 quad-chunks
    int c = cid >> 5, ec = cid & 31, e0 = ec*4;
    int rl = (ntb&7)*128 + c;
    float4 v = *(const float4*)(Wih + (size_t)rl*EMB_ + e0);
    int g = ec & 3, hi = (ec>>2)&1, kt = ec>>3;
    int lane = g*16 + (c&15), nt = c>>4;
    *(f16x4v*)&Bf[(((nt*4+kt)*64 + lane)<<3) + hi*4] = cvt4(v);
  }
  __syncthreads();

  const int w = tid>>6, l64 = tid&63, gq = l64>>4, r = l64&15;
  const float* bih = dir ? bihB : bihF;
  const float* bhh = dir ? bhhB : bhhF;
  for (int nt = 0; nt < 8; ++nt) {
    f32x4 acc = {0.f,0.f,0.f,0.f};
    for (int kt = 0; kt < 4; ++kt) {
      f16x8v a = *(f16x8v*)&Af[((w*4+kt)*64 + l64)<<3];
      f16x8v b = *(f16x8v*)&Bf[((nt*4+kt)*64 + l64)<<3];
      acc = MFMA(a,b,acc);
    }
    int col = nt*16 + r;
    int rl  = (ntb&7)*128 + col;
    float bias = bih[rl] + bhh[rl];
    f16x4v o4 = {(_Float16)(acc[0]+bias),(_Float16)(acc[1]+bias),
                 (_Float16)(acc[2]+bias),(_Float16)(acc[3]+bias)};
    // b = w*16 + 4*gq + reg  (contiguous in reg) -> one b64 write
    *(f16x4v*)&Tt[col*64 + w*16 + gq*4] = o4;
  }
  __syncthreads();
  _Float16* gdst = wx + ((size_t)(dir*L_ + l)*1024 + (size_t)(ntb&7)*128)*64;
  for (int q = 0; q < 4; ++q) {
    int idx = tid*32 + q*8;
    *(f16x8v*)(gdst + idx) = *(f16x8v*)&Tt[idx];
  }
}

// ---------------- Phase 2: grid-synced LSTM scan (both dirs concurrently)
// 32 blocks = 2 dirs x 16 unit-groups (16 units each). Whh fragments persistent
// in LDS; h exchanged through global memory in MFMA A-fragment order; c in regs.
__global__ __launch_bounds__(256) void k_scan(
    const float* __restrict__ WhhF, const float* __restrict__ WhhB,
    const _Float16* __restrict__ wx,
    _Float16* __restrict__ hfrag, _Float16* __restrict__ hist,
    unsigned* __restrict__ ctr)
{
  __shared__ _Float16 Wf[4*8*64*8];   // 32 KB  Whh B-fragments [nt(gate)][kt][lane][8]
  __shared__ _Float16 hA[4*8*64*8];   // 32 KB  h A-fragments (reloaded each step)
  __shared__ _Float16 Ht[4*64*4];     // 2 KB   new-h staging tile [mt][laneA][j]
  const int bid = blockIdx.x;
  const int dir = bid >> 4;
  const int ug  = bid & 15;
  const int tid = threadIdx.x;
  const int w = tid>>6, l64 = tid&63, gq = l64>>4, r = l64&15;
  const int KT = ug>>1, HI = ug&1;    // this block's k-slot in the A-fragment space

  const float* Whh = dir ? WhhB : WhhF;
  for (int it = 0; it < 8; ++it) {
    int fid = it*256 + tid;           // 2048 fragments
    int lane = fid & 63, kt = (fid>>6)&7, nt = fid>>9;
    int g = lane>>4, cr = lane&15;
    int row = nt*HID_ + ug*16 + cr;   // gate row (i,f,g,o blocks of 256)
    const float* src = Whh + (size_t)row*HID_ + kt*32 + g*4;
    float4 v1 = *(const float4*)(src);
    float4 v2 = *(const float4*)(src + 16);
    f16x8v p = {(_Float16)v1.x,(_Float16)v1.y,(_Float16)v1.z,(_Float16)v1.w,
                (_Float16)v2.x,(_Float16)v2.y,(_Float16)v2.z,(_Float16)v2.w};
    *(f16x8v*)&Wf[((nt*8+kt)*64 + lane)<<3] = p;
  }
  float cc0=0.f, cc1=0.f, cc2=0.f, cc3=0.f;   // cell state: 4 batches x my unit
  unsigned* myctr = ctr + dir*32;

  for (int t = 0; t < L_; ++t) {
    const int pos = dir ? (L_-1-t) : t;
    if (tid == 0) {
      if (t > 0) {
        unsigned tgt = 16u*(unsigned)t;
        while (__hip_atomic_load(myctr, __ATOMIC_RELAXED, __HIP_MEMORY_SCOPE_AGENT) < tgt)
          __builtin_amdgcn_s_sleep(1);
      }
      __threadfence();   // acquire: invalidate stale L1/L2 (cross-XCD)
    }
    __syncthreads();

    // prefetch Wx for my (unit, 4 batches): rows nt*256 + u, b = w*16+4gq+reg
    const _Float16* wxp = wx + ((size_t)(dir*L_ + pos)*1024 + (size_t)ug*16 + r)*64
                             + w*16 + gq*4;
    f16x4v x0 = *(const f16x4v*)(wxp + 0*16384);
    f16x4v x1 = *(const f16x4v*)(wxp + 1*16384);
    f16x4v x2 = *(const f16x4v*)(wxp + 2*16384);
    f16x4v x3 = *(const f16x4v*)(wxp + 3*16384);

    // load h fragments (32 KB, already in fragment order -> linear copy)
    const _Float16* hsrc = hfrag + (size_t)((t&1)*2 + dir)*16384;
    for (int it = 0; it < 8; ++it) {
      int idx = (it*256 + tid) << 3;
      *(f16x8v*)&hA[idx] = *(const f16x8v*)(hsrc + idx);
    }
    __syncthreads();

    f32x4 a0={0.f,0.f,0.f,0.f}, a1=a0, a2=a0, a3=a0;
    for (int kt = 0; kt < 8; ++kt) {
      f16x8v av = *(f16x8v*)&hA[((w*8+kt)*64 + l64)<<3];
      a0 = MFMA(av, *(f16x8v*)&Wf[((0*8+kt)*64 + l64)<<3], a0);
      a1 = MFMA(av, *(f16x8v*)&Wf[((1*8+kt)*64 + l64)<<3], a1);
      a2 = MFMA(av, *(f16x8v*)&Wf[((2*8+kt)*64 + l64)<<3], a2);
      a3 = MFMA(av, *(f16x8v*)&Wf[((3*8+kt)*64 + l64)<<3], a3);
    }

    float cc[4] = {cc0,cc1,cc2,cc3};
    #pragma unroll
    for (int reg = 0; reg < 4; ++reg) {
      float iv = sigf  (a0[reg] + (float)x0[reg]);
      float fv = sigf  (a1[reg] + (float)x1[reg]);
      float gv = tanhf_(a2[reg] + (float)x2[reg]);
      float ov = sigf  (a3[reg] + (float)x3[reg]);
      float c  = fv*cc[reg] + iv*gv;
      cc[reg]  = c;
      float hv = ov*tanhf_(c);
      // scatter into A-fragment position for unit u=ug*16+r, batch b=w*16+4gq+reg
      int laneA = (r>>2)*16 + gq*4 + reg;
      Ht[((w*64 + laneA)<<2) + (r&3)] = (_Float16)hv;
    }
    cc0=cc[0]; cc1=cc[1]; cc2=cc[2]; cc3=cc[3];
    __syncthreads();

    {  // coalesced global write: next-step h fragments + history archive
      int mt = tid>>6, laneA = tid&63;
      f16x4v hv4 = *(f16x4v*)&Ht[(mt*64 + laneA)<<2];
      size_t fidx = ((size_t)(mt*8 + KT)*64 + laneA)*8 + HI*4;
      *(f16x4v*)(hfrag + (size_t)(((t+1)&1)*2 + dir)*16384 + fidx) = hv4;
      *(f16x4v*)(hist  + (size_t)(dir*L_ + pos)*16384 + fidx) = hv4;
    }
    __syncthreads();   // barrier drains vmcnt -> all stores complete
    if (tid == 0) {
      __threadfence(); // release: write back dirty L2 (cross-XCD visibility)
      __hip_atomic_fetch_add(myctr, 1u, __ATOMIC_RELAXED, __HIP_MEMORY_SCOPE_AGENT);
    }
  }
}

// ---------------- Phase 3: emission GEMM (K=512, f16 MFMA) + CRF broadcast-add
// grid 512 (one block per l), block 256.
__global__ __launch_bounds__(256) void k_out(
    const _Float16* __restrict__ hist, const float* __restrict__ Wlin,
    const float* __restrict__ blin, const float* __restrict__ trans,
    float* __restrict__ out)
{
  __shared__ _Float16 Aa[2*16384];    // 64 KB  hcat fragments (fwd, bwd)
  __shared__ _Float16 Bf[2*16*64*8];  // 32 KB  W_lin fragments
  __shared__ float    em[64*32];      // 8 KB   emission tile
  __shared__ float    tt[1024];       // 4 KB   transition
  const int l = blockIdx.x;
  const int tid = threadIdx.x;

  for (int d = 0; d < 2; ++d)
    for (int it = 0; it < 8; ++it) {
      int idx = (it*256 + tid) << 3;
      *(f16x8v*)&Aa[d*16384 + idx] =
          *(const f16x8v*)(hist + (size_t)(d*L_ + l)*16384 + idx);
    }
  for (int it = 0; it < 8; ++it) {
    int fid = it*256 + tid;           // 2048 fragments
    int lane = fid & 63, ktc = (fid>>6)&15, nt = fid>>10;
    int o = nt*16 + (lane&15), g = lane>>4;
    const float* src = Wlin + (size_t)o*512 + ktc*32 + g*4;
    float4 v1 = *(const float4*)(src);
    float4 v2 = *(const float4*)(src + 16);
    f16x8v p = {(_Float16)v1.x,(_Float16)v1.y,(_Float16)v1.z,(_Float16)v1.w,
                (_Float16)v2.x,(_Float16)v2.y,(_Float16)v2.z,(_Float16)v2.w};
    *(f16x8v*)&Bf[((nt*16+ktc)*64 + lane)<<3] = p;
  }
  *(float4*)&tt[tid*4] = *(const float4*)(trans + tid*4);
  __syncthreads();

  const int w = tid>>6, l64 = tid&63, gq = l64>>4, r = l64&15;
  for (int nt = 0; nt < 2; ++nt) {
    f32x4 acc = {0.f,0.f,0.f,0.f};
    for (int ktc = 0; ktc < 16; ++ktc) {
      f16x8v a = *(f16x8v*)&Aa[(ktc>>3)*16384 + (((w*8 + (ktc&7))*64 + l64)<<3)];
      f16x8v b = *(f16x8v*)&Bf[((nt*16+ktc)*64 + l64)<<3];
      acc = MFMA(a,b,acc);
    }
    float bias = blin[nt*16 + r];
    #pragma unroll
    for (int reg = 0; reg < 4; ++reg)
      em[(w*16 + gq*4 + reg)*32 + nt*16 + r] = acc[reg] + bias;
  }
  __syncthreads();

  float4 tr4 = *(float4*)&tt[tid*4];                 // trans[i][j0..j0+3], i=tid>>3
  float* obase = out + (size_t)l*1024 + (size_t)tid*4;
  for (int b = 0; b < B_; ++b) {
    float4 e4 = *(float4*)&em[b*32 + (tid&7)*4];     // em[b][j0..j0+3]
    float4 o4 = {e4.x+tr4.x, e4.y+tr4.y, e4.z+tr4.z, e4.w+tr4.w};
    *(float4*)(obase + (size_t)b*(512*1024)) = o4;
  }
}

// ---------------- workspace layout (bytes)
//   [0, 131072)            h fragment double buffer: [buf2][dir2][16384 f16]
//   [131072, 131328)       barrier counters (2 dirs, separate cache lines)
//   [131328, +134217728)   Wx f16 [2][512][1024][64]
//   then    +33554432      hist f16 [2][512][16384]   -> total ~160.1 MiB
extern "C" void kernel_launch(void* const* d_in, const int* in_sizes, int n_in,
                              void* d_out, int out_size, void* d_ws, size_t ws_size,
                              hipStream_t stream)
{
  (void)in_sizes; (void)n_in; (void)out_size; (void)ws_size;
  const int*   sents = (const int*)  d_in[0];
  const float* emb   = (const float*)d_in[2];
  const float* WihF  = (const float*)d_in[3];
  const float* WhhF  = (const float*)d_in[4];
  const float* bihF  = (const float*)d_in[5];
  const float* bhhF  = (const float*)d_in[6];
  const float* WihB  = (const float*)d_in[7];
  const float* WhhB  = (const float*)d_in[8];
  const float* bihB  = (const float*)d_in[9];
  const float* bhhB  = (const float*)d_in[10];
  const float* Wlin  = (const float*)d_in[11];
  const float* blin  = (const float*)d_in[12];
  const float* trans = (const float*)d_in[13];
  float* out = (float*)d_out;

  char* ws = (char*)d_ws;
  _Float16* hfrag = (_Float16*)(ws + 0);
  unsigned* ctr   = (unsigned*)(ws + 131072);
  _Float16* wx    = (_Float16*)(ws + 131328);
  _Float16* hist  = (_Float16*)(ws + 131328 + 134217728);

  hipMemsetAsync(d_ws, 0, 131328, stream);   // zero h0 fragments + barrier ctrs
  hipLaunchKernelGGL(k_wx,   dim3(8192), dim3(256), 0, stream,
                     sents, emb, WihF, WihB, bihF, bhhF, bihB, bhhB, wx);
  hipLaunchKernelGGL(k_scan, dim3(32),   dim3(256), 0, stream,
                     WhhF, WhhB, wx, hfrag, hist, ctr);
  hipLaunchKernelGGL(k_out,  dim3(512),  dim3(256), 0, stream,
                     hist, Wlin, blin, trans, out);
}